// Round 2
// baseline (546.277 us; speedup 1.0000x reference)
//
#include <hip/hip_runtime.h>
#include <cstdint>

#define ENC_DEPTH 8
#define RAYS 64
#define THREADS 256

typedef __attribute__((ext_vector_type(8))) short bf16x8;
typedef __attribute__((ext_vector_type(4))) float f32x4;

__device__ __forceinline__ unsigned short f2bf(float x) {
    union { float f; unsigned u; } v; v.f = x;
    unsigned r = v.u + 0x7fffu + ((v.u >> 16) & 1u);
    return (unsigned short)(r >> 16);
}
__device__ __forceinline__ float clamp01(float x) {
    return fminf(fmaxf(x, 0.0f), 1.0f);
}
__device__ __forceinline__ void async_copy16(const float* g, void* l) {
    __builtin_amdgcn_global_load_lds(
        (const __attribute__((address_space(1))) void*)g,
        (__attribute__((address_space(3))) void*)l, 16, 0, 0);
}

// ---- helper: W1 (1024x64 fp32) -> fragment-major bf16 W1F in d_ws ----
// slot = ((d*4+kk)*4+tile)*64 + lane ; 8 bf16 per slot (j=0..7)
// value[j] = W1[(d*128+kk*32+(lane>>4)*8+j)*64 + tile*16+(lane&15)]
__global__ void w1_frag_kernel(const float* __restrict__ W1,
                               unsigned short* __restrict__ W1F) {
    int slot = blockIdx.x * 256 + threadIdx.x;   // 8192 slots
    int lane = slot & 63, tile = (slot >> 6) & 3, kk = (slot >> 8) & 3, d = slot >> 10;
    int n = tile * 16 + (lane & 15);
    int kbase = d * 128 + kk * 32 + (lane >> 4) * 8;
    bf16x8 v;
    #pragma unroll
    for (int j = 0; j < 8; ++j) v[j] = (short)f2bf(W1[(size_t)(kbase + j) * 64 + n]);
    *(bf16x8*)(W1F + (size_t)slot * 8) = v;
}

// LDS: cbuf[2] double-buffered fp32 corner rows, ray-pair regions of 1024B
// with 16B pad between pairs (stride 1040B = 260 floats) to break bank patterns.
__global__ __launch_bounds__(THREADS) void nbvh2(
    const float* __restrict__ orig, const float* __restrict__ endp,
    const int* __restrict__ hist, const float* __restrict__ nodes_min,
    const float* __restrict__ nodes_extent, const float* __restrict__ emb,
    const unsigned short* __restrict__ W1F, const float* __restrict__ W2,
    const float* __restrict__ W3, float* __restrict__ out)
{
    __shared__ __align__(16) float cbuf[2][8320];       // 2 x 33280 B
    __shared__ float pope_s[RAYS * ENC_DEPTH * 6];      // 12288 B
    __shared__ int hist_s[RAYS * ENC_DEPTH];            // 2048 B

    const int t = threadIdx.x;
    const int lane = t & 63, w = t >> 6;
    const int r0 = blockIdx.x * RAYS;

    // ---- stage history ----
    hist_s[t] = hist[r0 * ENC_DEPTH + t];
    hist_s[t + 256] = hist[r0 * ENC_DEPTH + t + 256];
    __syncthreads();

    // ---- issue DMA for depth 0 into cbuf[0] ----
    {
        #pragma unroll
        for (int r = 0; r < 8; ++r) {
            int ray = r * 8 + w * 2 + (lane >> 5);
            int node = hist_s[(ray << 3) + 0];
            const float* g = emb + ((size_t)node << 7) + ((lane & 31) << 2);
            char* l = (char*)(&cbuf[0][0]) + (r * 4 + w) * 1040 + lane * 16;
            async_copy16(g, l);
        }
    }

    // ---- prologue: po/pe for all (ray, depth) -> pope_s (overlaps DMA latency) ----
    #pragma unroll
    for (int rep = 0; rep < 2; ++rep) {
        int task = t + rep * 256;            // task = ray*8 + d
        int ray = task >> 3;
        int node = hist_s[task];
        float nm0 = nodes_min[node * 3 + 0], nm1 = nodes_min[node * 3 + 1], nm2 = nodes_min[node * 3 + 2];
        float ex0 = nodes_extent[node * 3 + 0], ex1 = nodes_extent[node * 3 + 1], ex2 = nodes_extent[node * 3 + 2];
        float o0 = orig[(r0 + ray) * 3 + 0], o1 = orig[(r0 + ray) * 3 + 1], o2 = orig[(r0 + ray) * 3 + 2];
        float e0 = endp[(r0 + ray) * 3 + 0], e1 = endp[(r0 + ray) * 3 + 1], e2 = endp[(r0 + ray) * 3 + 2];
        float* pp = pope_s + task * 6;
        pp[0] = clamp01((o0 - nm0) / ex0);
        pp[1] = clamp01((o1 - nm1) / ex1);
        pp[2] = clamp01((o2 - nm2) / ex2);
        pp[3] = clamp01((e0 - nm0) / ex0);
        pp[4] = clamp01((e1 - nm1) / ex1);
        pp[5] = clamp01((e2 - nm2) / ex2);
    }
    __syncthreads();   // drains DMA(0) + pope ready

    f32x4 acc[4];
    #pragma unroll
    for (int i = 0; i < 4; ++i) acc[i] = (f32x4){0.f, 0.f, 0.f, 0.f};

    const int c = lane & 15, q = lane >> 4;
    const int ray = w * 16 + c;              // this lane's A-row (m = c)
    const int qh = q & 1;                    // feature half
    const int qp = q >> 1;                   // point offset

    #pragma unroll 1
    for (int d = 0; d < ENC_DEPTH; ++d) {
        // ---- prefetch next depth's corners (async DMA) ----
        if (d < ENC_DEPTH - 1) {
            float* dst = &cbuf[(d + 1) & 1][0];
            #pragma unroll
            for (int r = 0; r < 8; ++r) {
                int rr = r * 8 + w * 2 + (lane >> 5);
                int node = hist_s[(rr << 3) + d + 1];
                const float* g = emb + ((size_t)node << 7) + ((lane & 31) << 2);
                char* l = (char*)dst + (r * 4 + w) * 1040 + lane * 16;
                async_copy16(g, l);
            }
        }

        // ---- B fragments (coalesced, L2-resident) ----
        bf16x8 bfr[4][4];
        #pragma unroll
        for (int kk = 0; kk < 4; ++kk)
            #pragma unroll
            for (int tile = 0; tile < 4; ++tile)
                bfr[kk][tile] = *(const bf16x8*)(W1F +
                    ((size_t)(((d * 4 + kk) * 4 + tile) * 64 + lane)) * 8);

        // ---- per-point axis values ----
        const float* pp = pope_s + ((ray << 3) + d) * 6;
        float po0 = pp[0], po1 = pp[1], po2 = pp[2], pe0 = pp[3], pe1 = pp[4], pe2 = pp[5];
        float X[4], OX[4], Y[4], OY[4], Z[4], OZ[4];
        #pragma unroll
        for (int kk = 0; kk < 4; ++kk) {
            float tp = (float)(2 * kk + qp) * (1.0f / 7.0f);
            X[kk] = po0 + (pe0 - po0) * tp; OX[kk] = 1.f - X[kk];
            Y[kk] = po1 + (pe1 - po1) * tp; OY[kk] = 1.f - Y[kk];
            Z[kk] = po2 + (pe2 - po2) * tp; OZ[kk] = 1.f - Z[kk];
        }

        // ---- interp: accumulate over 8 corners directly into A-frag values ----
        float fa[4][8];
        #pragma unroll
        for (int kk = 0; kk < 4; ++kk)
            #pragma unroll
            for (int j = 0; j < 8; ++j) fa[kk][j] = 0.f;

        const float* crow = &cbuf[d & 1][0] + (ray >> 1) * 260 + (ray & 1) * 128 + (qh << 3);
        #pragma unroll
        for (int c8 = 0; c8 < 8; ++c8) {
            float4 ea = *(const float4*)(crow + c8 * 16);
            float4 eb = *(const float4*)(crow + c8 * 16 + 4);
            #pragma unroll
            for (int kk = 0; kk < 4; ++kk) {
                float wx = ((0xD2 >> c8) & 1) ? X[kk] : OX[kk];
                float wy = ((0xE4 >> c8) & 1) ? Y[kk] : OY[kk];
                float wz = ((0xB8 >> c8) & 1) ? Z[kk] : OZ[kk];
                float wgt = wx * wy * wz;
                fa[kk][0] = fmaf(wgt, ea.x, fa[kk][0]);
                fa[kk][1] = fmaf(wgt, ea.y, fa[kk][1]);
                fa[kk][2] = fmaf(wgt, ea.z, fa[kk][2]);
                fa[kk][3] = fmaf(wgt, ea.w, fa[kk][3]);
                fa[kk][4] = fmaf(wgt, eb.x, fa[kk][4]);
                fa[kk][5] = fmaf(wgt, eb.y, fa[kk][5]);
                fa[kk][6] = fmaf(wgt, eb.z, fa[kk][6]);
                fa[kk][7] = fmaf(wgt, eb.w, fa[kk][7]);
            }
        }

        // ---- pack to bf16 A-frags + MFMA ----
        #pragma unroll
        for (int kk = 0; kk < 4; ++kk) {
            bf16x8 af;
            #pragma unroll
            for (int j = 0; j < 8; ++j) af[j] = (short)f2bf(fa[kk][j]);
            #pragma unroll
            for (int tile = 0; tile < 4; ++tile)
                acc[tile] = __builtin_amdgcn_mfma_f32_16x16x32_bf16(af, bfr[kk][tile], acc[tile], 0, 0, 0);
        }
        __syncthreads();   // buf[d&1] reusable; drains DMA(d+1)
    }

    // ---- h1 = relu(acc) -> LDS (alias cbuf[0]), row stride 68 ----
    float* h1 = &cbuf[0][0];
    #pragma unroll
    for (int tile = 0; tile < 4; ++tile)
        #pragma unroll
        for (int r = 0; r < 4; ++r)
            h1[(w * 16 + q * 4 + r) * 68 + tile * 16 + c] = fmaxf(acc[tile][r], 0.f);
    __syncthreads();

    // ---- GEMM2: h2 = relu(h1 @ W2) (fp32), h2 aliases cbuf[1] ----
    float* h2 = &cbuf[1][0];
    {
        int ray2 = t >> 2, jg = (t & 3) << 4;
        float s[16];
        #pragma unroll
        for (int j = 0; j < 16; ++j) s[j] = 0.f;
        const float* hrow = h1 + ray2 * 68;
        #pragma unroll 4
        for (int i = 0; i < 64; ++i) {
            float hv = hrow[i];
            const float4* wr = (const float4*)(W2 + (i << 6) + jg);
            float4 a0 = wr[0], a1 = wr[1], a2 = wr[2], a3 = wr[3];
            s[0]  = fmaf(hv, a0.x, s[0]);  s[1]  = fmaf(hv, a0.y, s[1]);
            s[2]  = fmaf(hv, a0.z, s[2]);  s[3]  = fmaf(hv, a0.w, s[3]);
            s[4]  = fmaf(hv, a1.x, s[4]);  s[5]  = fmaf(hv, a1.y, s[5]);
            s[6]  = fmaf(hv, a1.z, s[6]);  s[7]  = fmaf(hv, a1.w, s[7]);
            s[8]  = fmaf(hv, a2.x, s[8]);  s[9]  = fmaf(hv, a2.y, s[9]);
            s[10] = fmaf(hv, a2.z, s[10]); s[11] = fmaf(hv, a2.w, s[11]);
            s[12] = fmaf(hv, a3.x, s[12]); s[13] = fmaf(hv, a3.y, s[13]);
            s[14] = fmaf(hv, a3.z, s[14]); s[15] = fmaf(hv, a3.w, s[15]);
        }
        float* h2row = h2 + ray2 * 68 + jg;
        #pragma unroll
        for (int j = 0; j < 16; ++j) h2row[j] = fmaxf(s[j], 0.f);
    }
    __syncthreads();

    // ---- GEMM3 + output ----
    if (t < 128) {
        int ray3 = t >> 1, cc = t & 1;
        const float* hrow = h2 + ray3 * 68;
        float a = 0.f;
        #pragma unroll 16
        for (int i = 0; i < 64; ++i) a = fmaf(hrow[i], W3[i * 2 + cc], a);
        if (cc) {
            float dx = endp[(r0 + ray3) * 3 + 0] - orig[(r0 + ray3) * 3 + 0];
            float dy = endp[(r0 + ray3) * 3 + 1] - orig[(r0 + ray3) * 3 + 1];
            float dz = endp[(r0 + ray3) * 3 + 2] - orig[(r0 + ray3) * 3 + 2];
            a *= sqrtf(dx * dx + dy * dy + dz * dz);
        }
        out[((r0 + ray3) << 1) + cc] = a;
    }
}

extern "C" void kernel_launch(void* const* d_in, const int* in_sizes, int n_in,
                              void* d_out, int out_size, void* d_ws, size_t ws_size,
                              hipStream_t stream) {
    const float* orig = (const float*)d_in[0];
    const float* endp = (const float*)d_in[1];
    const int*   hist = (const int*)d_in[2];
    const float* nmin = (const float*)d_in[3];
    const float* next = (const float*)d_in[4];
    const float* emb  = (const float*)d_in[5];
    const float* W1   = (const float*)d_in[6];
    const float* W2   = (const float*)d_in[7];
    const float* W3   = (const float*)d_in[8];
    float* out = (float*)d_out;
    unsigned short* W1F = (unsigned short*)d_ws;   // 128 KB

    w1_frag_kernel<<<dim3(32), dim3(256), 0, stream>>>(W1, W1F);

    const int n_rays = in_sizes[0] / 3;
    nbvh2<<<dim3(n_rays / RAYS), dim3(THREADS), 0, stream>>>(
        orig, endp, hist, nmin, next, emb, W1F, W2, W3, out);
}